// Round 1
// baseline (616.473 us; speedup 1.0000x reference)
//
#include <hip/hip_runtime.h>

#define A_DIM 6
#define HID_D 64
#define LATENT_D 64
#define GRU_IN_D 134
#define T_STEPS 128
#define N_ENV 10
#define BN_TOT 640

__device__ __forceinline__ float fast_sigmoid(float x) {
    // 1/(1+exp(-x))
    return __builtin_amdgcn_rcpf(1.0f + __builtin_amdgcn_exp2f(-1.4426950408889634f * x));
}
__device__ __forceinline__ float fast_tanh(float x) {
    // 1 - 2/(exp(2x)+1)
    return 1.0f - 2.0f * __builtin_amdgcn_rcpf(1.0f + __builtin_amdgcn_exp2f(2.8853900817779268f * x));
}

__global__ __launch_bounds__(64, 1)
void policy_kernel(const float* __restrict__ s_h,
                   const int*   __restrict__ a_h,
                   const float* __restrict__ b_z,
                   const float* __restrict__ conv1_w, const float* __restrict__ conv1_b,
                   const float* __restrict__ conv2_w, const float* __restrict__ conv2_b,
                   const float* __restrict__ fc_w,    const float* __restrict__ fc_b,
                   const float* __restrict__ emb,
                   const float* __restrict__ gru_wih, const float* __restrict__ gru_whh,
                   const float* __restrict__ gru_bih, const float* __restrict__ gru_bhh,
                   const float* __restrict__ mlp1_w,  const float* __restrict__ mlp1_b,
                   const float* __restrict__ mlp2_w,  const float* __restrict__ mlp2_b,
                   float* __restrict__ logits_out, float* __restrict__ mask_out)
{
    __shared__ __align__(16) float s0[512];     // [c][h][w] 8x8x8
    __shared__ __align__(16) float a1[1152];    // conv1 out [32][6*6]
    __shared__ __align__(16) float a2[512];     // conv2 out flat [oc*16+oh*4+ow]
    __shared__ __align__(16) float semb[64];
    __shared__ __align__(16) float gxc[192];    // step-invariant gx (+bih, +bhh for r,z)
    __shared__ __align__(16) float atab[6 * 192]; // per-action gx contribution
    __shared__ __align__(16) float hbuf[64];

    const int bn = blockIdx.x;        // 0..639
    const int j  = threadIdx.x;       // 0..63 (single wave)

    // ---- masks output: (a_h != 5) ----
    {
        const int base = bn * T_STEPS;
        #pragma unroll
        for (int i = 0; i < 2; ++i) {
            const int t = j + i * 64;
            mask_out[base + t] = (a_h[base + t] != (A_DIM - 1)) ? 1.0f : 0.0f;
        }
    }

    // ---- load frame 0 of this sample ----
    {
        const float* src = s_h + (size_t)bn * T_STEPS * 512;
        #pragma unroll
        for (int i = 0; i < 8; ++i) s0[j + i * 64] = src[j + i * 64];
    }
    __syncthreads();

    // ---- conv1: (8,8,8) -> (32,6,6), ReLU ----
    for (int i = j; i < 1152; i += 64) {
        const int oc = i / 36, r = i % 36, oh = r / 6, ow = r % 6;
        float sum = conv1_b[oc];
        const float* wp = conv1_w + oc * 72;
        #pragma unroll
        for (int ic = 0; ic < 8; ++ic)
            #pragma unroll
            for (int kh = 0; kh < 3; ++kh)
                #pragma unroll
                for (int kw = 0; kw < 3; ++kw)
                    sum = fmaf(s0[ic * 64 + (oh + kh) * 8 + (ow + kw)],
                               wp[ic * 9 + kh * 3 + kw], sum);
        a1[i] = fmaxf(sum, 0.0f);
    }
    __syncthreads();

    // ---- conv2: (32,6,6) -> (32,4,4), ReLU; flat idx matches reshape(BN,-1) ----
    for (int i = j; i < 512; i += 64) {
        const int oc = i / 16, r = i % 16, oh = r / 4, ow = r % 4;
        float sum = conv2_b[oc];
        const float* wp = conv2_w + oc * 288;
        for (int ic = 0; ic < 32; ++ic)
            #pragma unroll
            for (int kh = 0; kh < 3; ++kh)
                #pragma unroll
                for (int kw = 0; kw < 3; ++kw)
                    sum = fmaf(a1[ic * 36 + (oh + kh) * 6 + (ow + kw)],
                               wp[ic * 9 + kh * 3 + kw], sum);
        a2[i] = fmaxf(sum, 0.0f);
    }
    __syncthreads();

    // ---- fc: 512 -> 64, ReLU (lane j computes semb[j]) ----
    {
        float s0a = fc_b[j], s1a = 0.f, s2a = 0.f, s3a = 0.f;
        const float* wp = fc_w + j * 512;
        for (int k = 0; k < 512; k += 4) {
            s0a = fmaf(a2[k + 0], wp[k + 0], s0a);
            s1a = fmaf(a2[k + 1], wp[k + 1], s1a);
            s2a = fmaf(a2[k + 2], wp[k + 2], s2a);
            s3a = fmaf(a2[k + 3], wp[k + 3], s3a);
        }
        semb[j] = fmaxf((s0a + s1a) + (s2a + s3a), 0.0f);
    }
    __syncthreads();

    // ---- step-invariant gx: gxc[g] = bih[g] + (bhh[g] for r,z) + semb@wih[:, :64] + bz@wih[:, 70:134] ----
    {
        const float* bz = b_z + (size_t)(bn / N_ENV) * LATENT_D;
        #pragma unroll
        for (int gi = 0; gi < 3; ++gi) {
            const int g = gi * 64 + j;
            float sum = gru_bih[g] + ((g < 128) ? gru_bhh[g] : 0.0f);
            const float* wp = gru_wih + g * GRU_IN_D;
            for (int k = 0; k < 64; ++k) sum = fmaf(semb[k], wp[k], sum);
            for (int k = 0; k < 64; ++k) sum = fmaf(bz[k], wp[70 + k], sum);
            gxc[g] = sum;
        }
    }
    // ---- action table: atab[a][g] = emb[a] @ wih[g, 64:70] ----
    for (int i = j; i < 6 * 192; i += 64) {
        const int a = i / 192, g = i % 192;
        float sum = 0.0f;
        #pragma unroll
        for (int q = 0; q < 6; ++q)
            sum = fmaf(emb[a * 6 + q], gru_wih[g * GRU_IN_D + 64 + q], sum);
        atab[i] = sum;
    }
    hbuf[j] = 0.0f;
    __syncthreads();

    // ---- preload recurrent weights into registers ----
    float wr[64], wz[64], wn[64], w1[64];
    {
        const float* pr = gru_whh + (size_t)j * 64;
        const float* pz = gru_whh + (size_t)(64 + j) * 64;
        const float* pn = gru_whh + (size_t)(128 + j) * 64;
        const float* p1 = mlp1_w + (size_t)j * 64;
        #pragma unroll
        for (int k = 0; k < 64; k += 4) {
            float4 v;
            v = *(const float4*)(pr + k); wr[k]=v.x; wr[k+1]=v.y; wr[k+2]=v.z; wr[k+3]=v.w;
            v = *(const float4*)(pz + k); wz[k]=v.x; wz[k+1]=v.y; wz[k+2]=v.z; wz[k+3]=v.w;
            v = *(const float4*)(pn + k); wn[k]=v.x; wn[k+1]=v.y; wn[k+2]=v.z; wn[k+3]=v.w;
            v = *(const float4*)(p1 + k); w1[k]=v.x; w1[k+1]=v.y; w1[k+2]=v.z; w1[k+3]=v.w;
        }
    }
    const float gxr = gxc[j], gxz = gxc[64 + j], gxn = gxc[128 + j];
    const float bhn = gru_bhh[128 + j];
    const float b1j = mlp1_b[j];
    float m2c[6], b2[6];
    #pragma unroll
    for (int o = 0; o < 6; ++o) { m2c[o] = mlp2_w[o * 64 + j]; b2[o] = mlp2_b[o]; }

    // ---- recurrent rollout: 127 steps, single wave, no barriers ----
    const float4* h4 = (const float4*)hbuf;
    float hprev = 0.0f;
    int act = A_DIM - 1;
    float* lout = logits_out + (size_t)bn * (T_STEPS - 1) * A_DIM;

    for (int t = 0; t < T_STEPS - 1; ++t) {
        const float* at = atab + act * 192;
        const float xr = gxr + at[j];
        const float xz = gxz + at[64 + j];
        const float xn = gxn + at[128 + j];

        float hr = 0.0f, hz = 0.0f, hn = bhn;
        #pragma unroll
        for (int k4 = 0; k4 < 16; ++k4) {
            const float4 hv = h4[k4];
            const int k = 4 * k4;
            hr = fmaf(hv.x, wr[k+0], hr); hz = fmaf(hv.x, wz[k+0], hz); hn = fmaf(hv.x, wn[k+0], hn);
            hr = fmaf(hv.y, wr[k+1], hr); hz = fmaf(hv.y, wz[k+1], hz); hn = fmaf(hv.y, wn[k+1], hn);
            hr = fmaf(hv.z, wr[k+2], hr); hz = fmaf(hv.z, wz[k+2], hz); hn = fmaf(hv.z, wn[k+2], hn);
            hr = fmaf(hv.w, wr[k+3], hr); hz = fmaf(hv.w, wz[k+3], hz); hn = fmaf(hv.w, wn[k+3], hn);
        }
        const float r = fast_sigmoid(xr + hr);
        const float z = fast_sigmoid(xz + hz);
        const float n = fast_tanh(fmaf(r, hn, xn));
        const float hnew = fmaf(z, hprev - n, n);   // (1-z)*n + z*h
        hprev = hnew;

        __builtin_amdgcn_wave_barrier();
        hbuf[j] = hnew;
        __builtin_amdgcn_wave_barrier();

        // mlp1: hid[j] = tanh(h_new @ mlp1_w[j] + b)
        float a0 = b1j, a1v = 0.f, a2v = 0.f, a3v = 0.f;
        #pragma unroll
        for (int k4 = 0; k4 < 16; ++k4) {
            const float4 hv = h4[k4];
            const int k = 4 * k4;
            a0 = fmaf(hv.x, w1[k+0], a0);
            a1v = fmaf(hv.y, w1[k+1], a1v);
            a2v = fmaf(hv.z, w1[k+2], a2v);
            a3v = fmaf(hv.w, w1[k+3], a3v);
        }
        const float hid = fast_tanh((a0 + a1v) + (a2v + a3v));

        // mlp2 via butterfly reduction: every lane ends with all 6 logits
        float p0 = hid * m2c[0], p1 = hid * m2c[1], p2 = hid * m2c[2];
        float p3 = hid * m2c[3], p4 = hid * m2c[4], p5 = hid * m2c[5];
        #pragma unroll
        for (int m = 32; m >= 1; m >>= 1) {
            p0 += __shfl_xor(p0, m, 64);
            p1 += __shfl_xor(p1, m, 64);
            p2 += __shfl_xor(p2, m, 64);
            p3 += __shfl_xor(p3, m, 64);
            p4 += __shfl_xor(p4, m, 64);
            p5 += __shfl_xor(p5, m, 64);
        }
        const float l0 = p0 + b2[0], l1 = p1 + b2[1], l2 = p2 + b2[2];
        const float l3 = p3 + b2[3], l4 = p4 + b2[4], l5 = p5 + b2[5];

        // argmax, first-max-wins (strict >)
        float best = l0; int bi = 0;
        if (l1 > best) { best = l1; bi = 1; }
        if (l2 > best) { best = l2; bi = 2; }
        if (l3 > best) { best = l3; bi = 3; }
        if (l4 > best) { best = l4; bi = 4; }
        if (l5 > best) { best = l5; bi = 5; }
        act = bi;

        const float outv = (j == 0) ? l0 : (j == 1) ? l1 : (j == 2) ? l2
                         : (j == 3) ? l3 : (j == 4) ? l4 : l5;
        if (j < A_DIM) lout[t * A_DIM + j] = outv;
    }
}

extern "C" void kernel_launch(void* const* d_in, const int* in_sizes, int n_in,
                              void* d_out, int out_size, void* d_ws, size_t ws_size,
                              hipStream_t stream) {
    const float* s_h     = (const float*)d_in[0];
    const int*   a_h     = (const int*)  d_in[1];
    const float* b_z     = (const float*)d_in[2];
    const float* conv1_w = (const float*)d_in[3];
    const float* conv1_b = (const float*)d_in[4];
    const float* conv2_w = (const float*)d_in[5];
    const float* conv2_b = (const float*)d_in[6];
    const float* fc_w    = (const float*)d_in[7];
    const float* fc_b    = (const float*)d_in[8];
    const float* emb     = (const float*)d_in[9];
    const float* gru_wih = (const float*)d_in[10];
    const float* gru_whh = (const float*)d_in[11];
    const float* gru_bih = (const float*)d_in[12];
    const float* gru_bhh = (const float*)d_in[13];
    const float* mlp1_w  = (const float*)d_in[14];
    const float* mlp1_b  = (const float*)d_in[15];
    const float* mlp2_w  = (const float*)d_in[16];
    const float* mlp2_b  = (const float*)d_in[17];

    float* out = (float*)d_out;
    float* logits_out = out;                                 // (B,N,127,6)
    float* mask_out   = out + (size_t)BN_TOT * (T_STEPS - 1) * A_DIM; // (B,N,128,1)

    policy_kernel<<<BN_TOT, 64, 0, stream>>>(
        s_h, a_h, b_z, conv1_w, conv1_b, conv2_w, conv2_b, fc_w, fc_b, emb,
        gru_wih, gru_whh, gru_bih, gru_bhh, mlp1_w, mlp1_b, mlp2_w, mlp2_b,
        logits_out, mask_out);
}

// Round 2
// 523.933 us; speedup vs baseline: 1.1766x; 1.1766x over previous
//
#include <hip/hip_runtime.h>

#define A_DIM 6
#define HID_D 64
#define LATENT_D 64
#define GRU_IN_D 134
#define T_STEPS 128
#define N_ENV 10
#define BN_TOT 640

typedef float f2 __attribute__((ext_vector_type(2)));

__device__ __forceinline__ float fast_sigmoid(float x) {
    return __builtin_amdgcn_rcpf(1.0f + __builtin_amdgcn_exp2f(-1.4426950408889634f * x));
}
__device__ __forceinline__ float fast_tanh(float x) {
    return 1.0f - 2.0f * __builtin_amdgcn_rcpf(1.0f + __builtin_amdgcn_exp2f(2.8853900817779268f * x));
}

template<int CTRL>
__device__ __forceinline__ float dppadd(float v) {
    int t = __builtin_amdgcn_update_dpp(0, __builtin_bit_cast(int, v), CTRL, 0xf, 0xf, true);
    return v + __builtin_bit_cast(float, t);
}
// sum over all 64 lanes, result returned as wave-uniform scalar
__device__ __forceinline__ float wave_reduce_add(float v) {
    v = dppadd<0x111>(v);   // row_shr:1
    v = dppadd<0x112>(v);   // row_shr:2
    v = dppadd<0x114>(v);   // row_shr:4
    v = dppadd<0x118>(v);   // row_shr:8  -> lane15 of each row has row sum
    v = dppadd<0x142>(v);   // row_bcast:15
    v = dppadd<0x143>(v);   // row_bcast:31 -> lane 63 has total
    return __builtin_bit_cast(float, __builtin_amdgcn_readlane(__builtin_bit_cast(int, v), 63));
}

__global__ __launch_bounds__(128, 1)
void policy_kernel(const float* __restrict__ s_h,
                   const int*   __restrict__ a_h,
                   const float* __restrict__ b_z,
                   const float* __restrict__ conv1_w, const float* __restrict__ conv1_b,
                   const float* __restrict__ conv2_w, const float* __restrict__ conv2_b,
                   const float* __restrict__ fc_w,    const float* __restrict__ fc_b,
                   const float* __restrict__ emb,
                   const float* __restrict__ gru_wih, const float* __restrict__ gru_whh,
                   const float* __restrict__ gru_bih, const float* __restrict__ gru_bhh,
                   const float* __restrict__ mlp1_w,  const float* __restrict__ mlp1_b,
                   const float* __restrict__ mlp2_w,  const float* __restrict__ mlp2_b,
                   float* __restrict__ logits_out, float* __restrict__ mask_out)
{
    __shared__ __align__(16) float s0[512];      // frame0 [c][h][w]
    __shared__ __align__(16) float a1[1152];     // conv1 out [32][36]
    __shared__ __align__(16) float a2[512];      // conv2 out flat
    __shared__ __align__(16) float pfc[128];     // fc partials
    __shared__ __align__(16) float semb[64];
    __shared__ __align__(16) float gxc[192];     // step-invariant gx (+biases)
    __shared__ __align__(16) float atab[6*192];  // per-action gx contribution
    __shared__ __align__(16) float hbuf[64];
    __shared__ __align__(16) f2   partA[128];    // {pr,pz} per (wave,lane)
    __shared__ __align__(16) f2   partB[128];    // {pn,p1}

    const int bn  = blockIdx.x;          // 0..639
    const int tid = threadIdx.x;         // 0..127
    const int j   = tid & 63;            // lane within wave
    const int w   = tid >> 6;            // wave id 0/1

    // ---- masks output: (a_h != 5), one elem per thread ----
    mask_out[bn * T_STEPS + tid] = (a_h[bn * T_STEPS + tid] != (A_DIM - 1)) ? 1.0f : 0.0f;

    // ---- load frame 0 ----
    {
        const float* src = s_h + (size_t)bn * T_STEPS * 512;
        #pragma unroll
        for (int i = 0; i < 4; ++i) s0[tid + i * 128] = src[tid + i * 128];
    }
    __syncthreads();

    // ---- conv1: (8,8,8) -> (32,6,6), ReLU ----
    for (int i = tid; i < 1152; i += 128) {
        const int oc = i / 36, r = i % 36, oh = r / 6, ow = r % 6;
        float sum = conv1_b[oc];
        const float* wp = conv1_w + oc * 72;
        #pragma unroll
        for (int ic = 0; ic < 8; ++ic)
            #pragma unroll
            for (int kh = 0; kh < 3; ++kh)
                #pragma unroll
                for (int kw = 0; kw < 3; ++kw)
                    sum = fmaf(s0[ic * 64 + (oh + kh) * 8 + (ow + kw)],
                               wp[ic * 9 + kh * 3 + kw], sum);
        a1[i] = fmaxf(sum, 0.0f);
    }
    __syncthreads();

    // ---- conv2: (32,6,6) -> (32,4,4), ReLU ----
    for (int i = tid; i < 512; i += 128) {
        const int oc = i / 16, r = i % 16, oh = r / 4, ow = r % 4;
        float sum = conv2_b[oc];
        const float* wp = conv2_w + oc * 288;
        for (int ic = 0; ic < 32; ++ic)
            #pragma unroll
            for (int kh = 0; kh < 3; ++kh)
                #pragma unroll
                for (int kw = 0; kw < 3; ++kw)
                    sum = fmaf(a1[ic * 36 + (oh + kh) * 6 + (ow + kw)],
                               wp[ic * 9 + kh * 3 + kw], sum);
        a2[i] = fmaxf(sum, 0.0f);
    }
    __syncthreads();

    // ---- fc: 512 -> 64, ReLU (k-split across the 2 waves) ----
    {
        const int o = j, hf = w;
        const float* wp = fc_w + o * 512 + hf * 256;
        const float* ap = a2 + hf * 256;
        float s0a = 0.f, s1a = 0.f, s2a = 0.f, s3a = 0.f;
        for (int k = 0; k < 256; k += 4) {
            s0a = fmaf(ap[k + 0], wp[k + 0], s0a);
            s1a = fmaf(ap[k + 1], wp[k + 1], s1a);
            s2a = fmaf(ap[k + 2], wp[k + 2], s2a);
            s3a = fmaf(ap[k + 3], wp[k + 3], s3a);
        }
        pfc[tid] = (s0a + s1a) + (s2a + s3a);
    }
    __syncthreads();
    if (tid < 64) semb[tid] = fmaxf(pfc[tid] + pfc[tid + 64] + fc_b[tid], 0.0f);
    __syncthreads();

    // ---- step-invariant gx ----
    {
        const float* bz = b_z + (size_t)(bn / N_ENV) * LATENT_D;
        for (int g = tid; g < 192; g += 128) {
            float sum = gru_bih[g] + ((g < 128) ? gru_bhh[g] : 0.0f);
            const float* wp = gru_wih + g * GRU_IN_D;
            for (int k = 0; k < 64; ++k) sum = fmaf(semb[k], wp[k], sum);
            for (int k = 0; k < 64; ++k) sum = fmaf(bz[k], wp[70 + k], sum);
            gxc[g] = sum;
        }
    }
    // ---- action table ----
    for (int i = tid; i < 6 * 192; i += 128) {
        const int a = i / 192, g = i % 192;
        float sum = 0.0f;
        #pragma unroll
        for (int q = 0; q < 6; ++q)
            sum = fmaf(emb[a * 6 + q], gru_wih[g * GRU_IN_D + 64 + q], sum);
        atab[i] = sum;
    }
    __syncthreads();

    // ---- per-lane register state ----
    // weights: lane (w,j) holds k-chunk [32w, 32w+32) of rows {j, 64+j, 128+j} of whh and row j of mlp1
    f2 wr[16], wz[16], wn[16], w1[16];
    {
        const float* pr = gru_whh + (size_t)j * 64 + 32 * w;
        const float* pz = gru_whh + (size_t)(64 + j) * 64 + 32 * w;
        const float* pn = gru_whh + (size_t)(128 + j) * 64 + 32 * w;
        const float* p1 = mlp1_w + (size_t)j * 64 + 32 * w;
        #pragma unroll
        for (int i = 0; i < 8; ++i) {
            float4 v;
            v = ((const float4*)pr)[i]; wr[2*i] = (f2){v.x, v.y}; wr[2*i+1] = (f2){v.z, v.w};
            v = ((const float4*)pz)[i]; wz[2*i] = (f2){v.x, v.y}; wz[2*i+1] = (f2){v.z, v.w};
            v = ((const float4*)pn)[i]; wn[2*i] = (f2){v.x, v.y}; wn[2*i+1] = (f2){v.z, v.w};
            v = ((const float4*)p1)[i]; w1[2*i] = (f2){v.x, v.y}; w1[2*i+1] = (f2){v.z, v.w};
        }
    }
    const float gxr = gxc[j], gxz = gxc[64 + j], gxn = gxc[128 + j];
    const float bhn = gru_bhh[128 + j];
    const float b1j = mlp1_b[j];
    float ar[6], az[6], an[6], m2c[6], b2[6];
    #pragma unroll
    for (int a = 0; a < 6; ++a) {
        ar[a] = atab[a * 192 + j];
        az[a] = atab[a * 192 + 64 + j];
        an[a] = atab[a * 192 + 128 + j];
        m2c[a] = mlp2_w[a * 64 + j];
        b2[a] = mlp2_b[a];
    }

    // ---- rollout ----
    float hprev = 0.0f;
    float hr_c = 0.0f, hz_c = 0.0f, hn_c = bhn;   // gh dots for h_t (h_0 = 0)
    int act = A_DIM - 1;
    float* lout = logits_out + (size_t)bn * (T_STEPS - 1) * A_DIM;
    const float4* hv4 = (const float4*)hbuf + w * 8;

    for (int t = 0; t < T_STEPS - 1; ++t) {
        // select action contribution (act is uniform)
        float sr = ar[0], sz = az[0], sn = an[0];
        #pragma unroll
        for (int a = 1; a < 6; ++a) {
            const bool c = (act == a);
            sr = c ? ar[a] : sr; sz = c ? az[a] : sz; sn = c ? an[a] : sn;
        }
        const float r = fast_sigmoid(gxr + sr + hr_c);
        const float z = fast_sigmoid(gxz + sz + hz_c);
        const float n = fast_tanh(fmaf(r, hn_c, gxn + sn));
        const float hnew = fmaf(z, hprev - n, n);
        hprev = hnew;

        if (w == 0) hbuf[j] = hnew;
        __syncthreads();

        // fused sweep over hnew: partial dots for next-step gh AND this-step mlp1
        f2 pr = {0.f, 0.f}, pz = {0.f, 0.f}, pn = {0.f, 0.f}, p1 = {0.f, 0.f};
        #pragma unroll
        for (int i = 0; i < 8; ++i) {
            const float4 hv = hv4[i];
            const f2 ha = (f2){hv.x, hv.y};
            const f2 hb = (f2){hv.z, hv.w};
            pr += ha * wr[2*i]; pr += hb * wr[2*i+1];
            pz += ha * wz[2*i]; pz += hb * wz[2*i+1];
            pn += ha * wn[2*i]; pn += hb * wn[2*i+1];
            p1 += ha * w1[2*i]; p1 += hb * w1[2*i+1];
        }
        const float mr = pr.x + pr.y, mz = pz.x + pz.y;
        const float mn = pn.x + pn.y, m1 = p1.x + p1.y;
        partA[(w << 6) | j] = (f2){mr, mz};
        partB[(w << 6) | j] = (f2){mn, m1};
        __syncthreads();
        const f2 oA = partA[((1 - w) << 6) | j];
        const f2 oB = partB[((1 - w) << 6) | j];
        hr_c = mr + oA.x;
        hz_c = mz + oA.y;
        hn_c = mn + oB.x + bhn;
        const float h1f = m1 + oB.y + b1j;

        const float hid = fast_tanh(h1f);

        // mlp2 + bias via DPP wave reduction (computed redundantly in both waves)
        const float l0 = wave_reduce_add(hid * m2c[0]) + b2[0];
        const float l1 = wave_reduce_add(hid * m2c[1]) + b2[1];
        const float l2 = wave_reduce_add(hid * m2c[2]) + b2[2];
        const float l3 = wave_reduce_add(hid * m2c[3]) + b2[3];
        const float l4 = wave_reduce_add(hid * m2c[4]) + b2[4];
        const float l5 = wave_reduce_add(hid * m2c[5]) + b2[5];

        // argmax, first-max-wins
        float best = l0; int bi = 0;
        if (l1 > best) { best = l1; bi = 1; }
        if (l2 > best) { best = l2; bi = 2; }
        if (l3 > best) { best = l3; bi = 3; }
        if (l4 > best) { best = l4; bi = 4; }
        if (l5 > best) { best = l5; bi = 5; }
        act = bi;

        if (tid < A_DIM) {
            const float outv = (j == 0) ? l0 : (j == 1) ? l1 : (j == 2) ? l2
                             : (j == 3) ? l3 : (j == 4) ? l4 : l5;
            lout[t * A_DIM + j] = outv;
        }
    }
}

extern "C" void kernel_launch(void* const* d_in, const int* in_sizes, int n_in,
                              void* d_out, int out_size, void* d_ws, size_t ws_size,
                              hipStream_t stream) {
    const float* s_h     = (const float*)d_in[0];
    const int*   a_h     = (const int*)  d_in[1];
    const float* b_z     = (const float*)d_in[2];
    const float* conv1_w = (const float*)d_in[3];
    const float* conv1_b = (const float*)d_in[4];
    const float* conv2_w = (const float*)d_in[5];
    const float* conv2_b = (const float*)d_in[6];
    const float* fc_w    = (const float*)d_in[7];
    const float* fc_b    = (const float*)d_in[8];
    const float* emb     = (const float*)d_in[9];
    const float* gru_wih = (const float*)d_in[10];
    const float* gru_whh = (const float*)d_in[11];
    const float* gru_bih = (const float*)d_in[12];
    const float* gru_bhh = (const float*)d_in[13];
    const float* mlp1_w  = (const float*)d_in[14];
    const float* mlp1_b  = (const float*)d_in[15];
    const float* mlp2_w  = (const float*)d_in[16];
    const float* mlp2_b  = (const float*)d_in[17];

    float* out = (float*)d_out;
    float* logits_out = out;                                          // (B,N,127,6)
    float* mask_out   = out + (size_t)BN_TOT * (T_STEPS - 1) * A_DIM; // (B,N,128,1)

    policy_kernel<<<BN_TOT, 128, 0, stream>>>(
        s_h, a_h, b_z, conv1_w, conv1_b, conv2_w, conv2_b, fc_w, fc_b, emb,
        gru_wih, gru_whh, gru_bih, gru_bhh, mlp1_w, mlp1_b, mlp2_w, mlp2_b,
        logits_out, mask_out);
}

// Round 3
// 516.987 us; speedup vs baseline: 1.1924x; 1.0134x over previous
//
#include <hip/hip_runtime.h>

#define A_DIM 6
#define HID_D 64
#define LATENT_D 64
#define GRU_IN_D 134
#define T_STEPS 128
#define N_ENV 10
#define BN_TOT 640

typedef float f2 __attribute__((ext_vector_type(2)));

__device__ __forceinline__ float fast_sigmoid(float x) {
    return __builtin_amdgcn_rcpf(1.0f + __builtin_amdgcn_exp2f(-1.4426950408889634f * x));
}
__device__ __forceinline__ float fast_tanh(float x) {
    return 1.0f - 2.0f * __builtin_amdgcn_rcpf(1.0f + __builtin_amdgcn_exp2f(2.8853900817779268f * x));
}

template<int CTRL>
__device__ __forceinline__ float dppadd(float v) {
    int t = __builtin_amdgcn_update_dpp(0, __builtin_bit_cast(int, v), CTRL, 0xf, 0xf, true);
    return v + __builtin_bit_cast(float, t);
}
// sum over all 64 lanes -> wave-uniform scalar
__device__ __forceinline__ float wave_reduce_add(float v) {
    v = dppadd<0x111>(v);   // row_shr:1
    v = dppadd<0x112>(v);   // row_shr:2
    v = dppadd<0x114>(v);   // row_shr:4
    v = dppadd<0x118>(v);   // row_shr:8
    v = dppadd<0x142>(v);   // row_bcast:15
    v = dppadd<0x143>(v);   // row_bcast:31 -> lane 63 has total
    return __builtin_bit_cast(float, __builtin_amdgcn_readlane(__builtin_bit_cast(int, v), 63));
}

__global__ __launch_bounds__(128, 1)
void policy_kernel(const float* __restrict__ s_h,
                   const int*   __restrict__ a_h,
                   const float* __restrict__ b_z,
                   const float* __restrict__ conv1_w, const float* __restrict__ conv1_b,
                   const float* __restrict__ conv2_w, const float* __restrict__ conv2_b,
                   const float* __restrict__ fc_w,    const float* __restrict__ fc_b,
                   const float* __restrict__ emb,
                   const float* __restrict__ gru_wih, const float* __restrict__ gru_whh,
                   const float* __restrict__ gru_bih, const float* __restrict__ gru_bhh,
                   const float* __restrict__ mlp1_w,  const float* __restrict__ mlp1_b,
                   const float* __restrict__ mlp2_w,  const float* __restrict__ mlp2_b,
                   float* __restrict__ logits_out, float* __restrict__ mask_out)
{
    __shared__ __align__(16) float s0[512];      // frame0 [c][h][w]
    __shared__ __align__(16) float a1[1152];     // conv1 out [32][36]
    __shared__ __align__(16) float a2[512];      // conv2 out flat
    __shared__ __align__(16) float pfc[128];     // fc partials
    __shared__ __align__(16) float semb[64];
    __shared__ __align__(16) float gxc[192];     // step-invariant gx (+biases)
    __shared__ __align__(16) float atab[6*192];  // per-action gx contribution
    __shared__ __align__(16) float hpriv[2][64]; // wave-private hnew broadcast buffers
    __shared__ __align__(16) float4 pex[2][2][64]; // [buf][wave][lane] = {mr,mz,mn,m1}

    const int bn  = blockIdx.x;          // 0..639
    const int tid = threadIdx.x;         // 0..127
    const int j   = tid & 63;            // lane within wave
    const int w   = tid >> 6;            // wave id 0/1

    // ---- masks output ----
    mask_out[bn * T_STEPS + tid] = (a_h[bn * T_STEPS + tid] != (A_DIM - 1)) ? 1.0f : 0.0f;

    // ---- load frame 0 ----
    {
        const float* src = s_h + (size_t)bn * T_STEPS * 512;
        #pragma unroll
        for (int i = 0; i < 4; ++i) s0[tid + i * 128] = src[tid + i * 128];
    }
    __syncthreads();

    // ---- conv1: (8,8,8) -> (32,6,6), ReLU ----
    for (int i = tid; i < 1152; i += 128) {
        const int oc = i / 36, r = i % 36, oh = r / 6, ow = r % 6;
        float sum = conv1_b[oc];
        const float* wp = conv1_w + oc * 72;
        #pragma unroll
        for (int ic = 0; ic < 8; ++ic)
            #pragma unroll
            for (int kh = 0; kh < 3; ++kh)
                #pragma unroll
                for (int kw = 0; kw < 3; ++kw)
                    sum = fmaf(s0[ic * 64 + (oh + kh) * 8 + (ow + kw)],
                               wp[ic * 9 + kh * 3 + kw], sum);
        a1[i] = fmaxf(sum, 0.0f);
    }
    __syncthreads();

    // ---- conv2: (32,6,6) -> (32,4,4), ReLU ----
    for (int i = tid; i < 512; i += 128) {
        const int oc = i / 16, r = i % 16, oh = r / 4, ow = r % 4;
        float sum = conv2_b[oc];
        const float* wp = conv2_w + oc * 288;
        for (int ic = 0; ic < 32; ++ic)
            #pragma unroll
            for (int kh = 0; kh < 3; ++kh)
                #pragma unroll
                for (int kw = 0; kw < 3; ++kw)
                    sum = fmaf(a1[ic * 36 + (oh + kh) * 6 + (ow + kw)],
                               wp[ic * 9 + kh * 3 + kw], sum);
        a2[i] = fmaxf(sum, 0.0f);
    }
    __syncthreads();

    // ---- fc: 512 -> 64, ReLU (k-split across 2 waves) ----
    {
        const float* wp = fc_w + j * 512 + w * 256;
        const float* ap = a2 + w * 256;
        float s0a = 0.f, s1a = 0.f, s2a = 0.f, s3a = 0.f;
        for (int k = 0; k < 256; k += 4) {
            s0a = fmaf(ap[k + 0], wp[k + 0], s0a);
            s1a = fmaf(ap[k + 1], wp[k + 1], s1a);
            s2a = fmaf(ap[k + 2], wp[k + 2], s2a);
            s3a = fmaf(ap[k + 3], wp[k + 3], s3a);
        }
        pfc[tid] = (s0a + s1a) + (s2a + s3a);
    }
    __syncthreads();
    if (tid < 64) semb[tid] = fmaxf(pfc[tid] + pfc[tid + 64] + fc_b[tid], 0.0f);
    __syncthreads();

    // ---- step-invariant gx ----
    {
        const float* bz = b_z + (size_t)(bn / N_ENV) * LATENT_D;
        for (int g = tid; g < 192; g += 128) {
            float sum = gru_bih[g] + ((g < 128) ? gru_bhh[g] : 0.0f);
            const float* wp = gru_wih + g * GRU_IN_D;
            for (int k = 0; k < 64; ++k) sum = fmaf(semb[k], wp[k], sum);
            for (int k = 0; k < 64; ++k) sum = fmaf(bz[k], wp[70 + k], sum);
            gxc[g] = sum;
        }
    }
    // ---- action table ----
    for (int i = tid; i < 6 * 192; i += 128) {
        const int a = i / 192, g = i % 192;
        float sum = 0.0f;
        #pragma unroll
        for (int q = 0; q < 6; ++q)
            sum = fmaf(emb[a * 6 + q], gru_wih[g * GRU_IN_D + 64 + q], sum);
        atab[i] = sum;
    }
    __syncthreads();

    // ---- per-lane register state ----
    // lane (w,j): k-chunk [32w,32w+32) of whh rows {j,64+j,128+j} and mlp1 row j
    f2 wr[16], wz[16], wn[16], w1[16];
    {
        const float* pr = gru_whh + (size_t)j * 64 + 32 * w;
        const float* pz = gru_whh + (size_t)(64 + j) * 64 + 32 * w;
        const float* pn = gru_whh + (size_t)(128 + j) * 64 + 32 * w;
        const float* p1 = mlp1_w + (size_t)j * 64 + 32 * w;
        #pragma unroll
        for (int i = 0; i < 8; ++i) {
            float4 v;
            v = ((const float4*)pr)[i]; wr[2*i] = (f2){v.x, v.y}; wr[2*i+1] = (f2){v.z, v.w};
            v = ((const float4*)pz)[i]; wz[2*i] = (f2){v.x, v.y}; wz[2*i+1] = (f2){v.z, v.w};
            v = ((const float4*)pn)[i]; wn[2*i] = (f2){v.x, v.y}; wn[2*i+1] = (f2){v.z, v.w};
            v = ((const float4*)p1)[i]; w1[2*i] = (f2){v.x, v.y}; w1[2*i+1] = (f2){v.z, v.w};
        }
    }
    const float gxr = gxc[j], gxz = gxc[64 + j], gxn = gxc[128 + j];
    const float bhn = gru_bhh[128 + j];
    const float b1j = mlp1_b[j];
    float ar[6], az[6], an[6], m2c[6], b2[6];
    #pragma unroll
    for (int a = 0; a < 6; ++a) {
        ar[a] = atab[a * 192 + j];
        az[a] = atab[a * 192 + 64 + j];
        an[a] = atab[a * 192 + 128 + j];
        m2c[a] = mlp2_w[a * 64 + j];
        b2[a] = mlp2_b[a];
    }

    // ---- rollout: 1 s_barrier per step ----
    float hprev = 0.0f;
    float hr_c = 0.0f, hz_c = 0.0f, hn_c = bhn;   // full gh dots for h_0 = 0
    int act = A_DIM - 1;
    float* lout = logits_out + (size_t)bn * (T_STEPS - 1) * A_DIM;
    const float4* hp4 = (const float4*)(&hpriv[w][0]) + w * 8;  // own k-half

    for (int t = 0; t < T_STEPS - 1; ++t) {
        // act is uniform; select action contribution from registers
        float sr = ar[0], sz = az[0], sn = an[0];
        #pragma unroll
        for (int a = 1; a < 6; ++a) {
            const bool c = (act == a);
            sr = c ? ar[a] : sr; sz = c ? az[a] : sz; sn = c ? an[a] : sn;
        }
        const float r = fast_sigmoid(gxr + sr + hr_c);
        const float z = fast_sigmoid(gxz + sz + hz_c);
        const float n = fast_tanh(fmaf(r, hn_c, gxn + sn));
        const float hnew = fmaf(z, hprev - n, n);
        hprev = hnew;

        // wave-private h broadcast (no cross-wave sync needed)
        __builtin_amdgcn_wave_barrier();
        hpriv[w][j] = hnew;
        __builtin_amdgcn_wave_barrier();

        // partial dots over own k-half for all 4 rows
        f2 pr = {0.f, 0.f}, pz = {0.f, 0.f}, pn = {0.f, 0.f}, p1 = {0.f, 0.f};
        #pragma unroll
        for (int i = 0; i < 8; ++i) {
            const float4 hv = hp4[i];
            const f2 ha = (f2){hv.x, hv.y};
            const f2 hb = (f2){hv.z, hv.w};
            pr += ha * wr[2*i]; pr += hb * wr[2*i+1];
            pz += ha * wz[2*i]; pz += hb * wz[2*i+1];
            pn += ha * wn[2*i]; pn += hb * wn[2*i+1];
            p1 += ha * w1[2*i]; p1 += hb * w1[2*i+1];
        }
        const float mr = pr.x + pr.y, mz = pz.x + pz.y;
        const float mn = pn.x + pn.y, m1 = p1.x + p1.y;

        // single-barrier exchange (double-buffered)
        pex[t & 1][w][j] = (float4){mr, mz, mn, m1};
        __syncthreads();
        const float4 o = pex[t & 1][w ^ 1][j];
        hr_c = mr + o.x;
        hz_c = mz + o.y;
        hn_c = mn + o.z + bhn;
        const float hid = fast_tanh(m1 + o.w + b1j);

        // mlp2 + argmax, computed redundantly in both waves
        const float l0 = wave_reduce_add(hid * m2c[0]) + b2[0];
        const float l1 = wave_reduce_add(hid * m2c[1]) + b2[1];
        const float l2 = wave_reduce_add(hid * m2c[2]) + b2[2];
        const float l3 = wave_reduce_add(hid * m2c[3]) + b2[3];
        const float l4 = wave_reduce_add(hid * m2c[4]) + b2[4];
        const float l5 = wave_reduce_add(hid * m2c[5]) + b2[5];

        float best = l0; int bi = 0;
        if (l1 > best) { best = l1; bi = 1; }
        if (l2 > best) { best = l2; bi = 2; }
        if (l3 > best) { best = l3; bi = 3; }
        if (l4 > best) { best = l4; bi = 4; }
        if (l5 > best) { best = l5; bi = 5; }
        act = bi;

        if (tid < A_DIM) {
            const float outv = (j == 0) ? l0 : (j == 1) ? l1 : (j == 2) ? l2
                             : (j == 3) ? l3 : (j == 4) ? l4 : l5;
            lout[t * A_DIM + j] = outv;
        }
    }
}

extern "C" void kernel_launch(void* const* d_in, const int* in_sizes, int n_in,
                              void* d_out, int out_size, void* d_ws, size_t ws_size,
                              hipStream_t stream) {
    const float* s_h     = (const float*)d_in[0];
    const int*   a_h     = (const int*)  d_in[1];
    const float* b_z     = (const float*)d_in[2];
    const float* conv1_w = (const float*)d_in[3];
    const float* conv1_b = (const float*)d_in[4];
    const float* conv2_w = (const float*)d_in[5];
    const float* conv2_b = (const float*)d_in[6];
    const float* fc_w    = (const float*)d_in[7];
    const float* fc_b    = (const float*)d_in[8];
    const float* emb     = (const float*)d_in[9];
    const float* gru_wih = (const float*)d_in[10];
    const float* gru_whh = (const float*)d_in[11];
    const float* gru_bih = (const float*)d_in[12];
    const float* gru_bhh = (const float*)d_in[13];
    const float* mlp1_w  = (const float*)d_in[14];
    const float* mlp1_b  = (const float*)d_in[15];
    const float* mlp2_w  = (const float*)d_in[16];
    const float* mlp2_b  = (const float*)d_in[17];

    float* out = (float*)d_out;
    float* logits_out = out;                                          // (B,N,127,6)
    float* mask_out   = out + (size_t)BN_TOT * (T_STEPS - 1) * A_DIM; // (B,N,128,1)

    policy_kernel<<<BN_TOT, 128, 0, stream>>>(
        s_h, a_h, b_z, conv1_w, conv1_b, conv2_w, conv2_b, fc_w, fc_b, emb,
        gru_wih, gru_whh, gru_bih, gru_bhh, mlp1_w, mlp1_b, mlp2_w, mlp2_b,
        logits_out, mask_out);
}

// Round 5
// 482.867 us; speedup vs baseline: 1.2767x; 1.0707x over previous
//
#include <hip/hip_runtime.h>

#define A_DIM 6
#define HID_D 64
#define LATENT_D 64
#define GRU_IN_D 134
#define T_STEPS 128
#define N_ENV 10
#define BN_TOT 640

typedef float f2 __attribute__((ext_vector_type(2)));

__device__ __forceinline__ float fast_sigmoid(float x) {
    return __builtin_amdgcn_rcpf(1.0f + __builtin_amdgcn_exp2f(-1.4426950408889634f * x));
}
__device__ __forceinline__ float fast_tanh(float x) {
    return 1.0f - 2.0f * __builtin_amdgcn_rcpf(1.0f + __builtin_amdgcn_exp2f(2.8853900817779268f * x));
}

template<int CTRL>
__device__ __forceinline__ float dppadd(float v) {
    int t = __builtin_amdgcn_update_dpp(0, __builtin_bit_cast(int, v), CTRL, 0xf, 0xf, true);
    return v + __builtin_bit_cast(float, t);
}
// sum over all 64 lanes -> wave-uniform scalar (VALU pipe only)
__device__ __forceinline__ float wave_reduce_add(float v) {
    v = dppadd<0x111>(v);   // row_shr:1
    v = dppadd<0x112>(v);   // row_shr:2
    v = dppadd<0x114>(v);   // row_shr:4
    v = dppadd<0x118>(v);   // row_shr:8
    v = dppadd<0x142>(v);   // row_bcast:15
    v = dppadd<0x143>(v);   // row_bcast:31 -> lane 63 has total
    return __builtin_bit_cast(float, __builtin_amdgcn_readlane(__builtin_bit_cast(int, v), 63));
}

__global__ __launch_bounds__(128, 1)
void policy_kernel(const float* __restrict__ s_h,
                   const int*   __restrict__ a_h,
                   const float* __restrict__ b_z,
                   const float* __restrict__ conv1_w, const float* __restrict__ conv1_b,
                   const float* __restrict__ conv2_w, const float* __restrict__ conv2_b,
                   const float* __restrict__ fc_w,    const float* __restrict__ fc_b,
                   const float* __restrict__ emb,
                   const float* __restrict__ gru_wih, const float* __restrict__ gru_whh,
                   const float* __restrict__ gru_bih, const float* __restrict__ gru_bhh,
                   const float* __restrict__ mlp1_w,  const float* __restrict__ mlp1_b,
                   const float* __restrict__ mlp2_w,  const float* __restrict__ mlp2_b,
                   float* __restrict__ logits_out, float* __restrict__ mask_out)
{
    __shared__ __align__(16) float s0[512];      // frame0 [c][h][w]
    __shared__ __align__(16) float a1[1152];     // conv1 out [32][36]
    __shared__ __align__(16) float a2[512];      // conv2 out flat
    __shared__ __align__(16) float pfc[128];     // fc partials
    __shared__ __align__(16) float semb[64];
    __shared__ __align__(16) float gxc[192];     // step-invariant gx (+biases)
    __shared__ __align__(16) float atab[6*192];  // per-action gx contribution
    __shared__ __align__(16) float hbuf[64];     // f32 hidden-state broadcast

    const int bn  = blockIdx.x;          // 0..639
    const int tid = threadIdx.x;         // 0..127 (preamble); rollout = wave 0 only
    const int j   = tid & 63;
    const int w   = tid >> 6;

    // ---- masks output ----
    mask_out[bn * T_STEPS + tid] = (a_h[bn * T_STEPS + tid] != (A_DIM - 1)) ? 1.0f : 0.0f;

    // ---- load frame 0 ----
    {
        const float* src = s_h + (size_t)bn * T_STEPS * 512;
        #pragma unroll
        for (int i = 0; i < 4; ++i) s0[tid + i * 128] = src[tid + i * 128];
    }
    __syncthreads();

    // ---- conv1: (8,8,8) -> (32,6,6), ReLU ----
    for (int i = tid; i < 1152; i += 128) {
        const int oc = i / 36, r = i % 36, oh = r / 6, ow = r % 6;
        float sum = conv1_b[oc];
        const float* wp = conv1_w + oc * 72;
        #pragma unroll
        for (int ic = 0; ic < 8; ++ic)
            #pragma unroll
            for (int kh = 0; kh < 3; ++kh)
                #pragma unroll
                for (int kw = 0; kw < 3; ++kw)
                    sum = fmaf(s0[ic * 64 + (oh + kh) * 8 + (ow + kw)],
                               wp[ic * 9 + kh * 3 + kw], sum);
        a1[i] = fmaxf(sum, 0.0f);
    }
    __syncthreads();

    // ---- conv2: (32,6,6) -> (32,4,4), ReLU ----
    for (int i = tid; i < 512; i += 128) {
        const int oc = i / 16, r = i % 16, oh = r / 4, ow = r % 4;
        float sum = conv2_b[oc];
        const float* wp = conv2_w + oc * 288;
        for (int ic = 0; ic < 32; ++ic)
            #pragma unroll
            for (int kh = 0; kh < 3; ++kh)
                #pragma unroll
                for (int kw = 0; kw < 3; ++kw)
                    sum = fmaf(a1[ic * 36 + (oh + kh) * 6 + (ow + kw)],
                               wp[ic * 9 + kh * 3 + kw], sum);
        a2[i] = fmaxf(sum, 0.0f);
    }
    __syncthreads();

    // ---- fc: 512 -> 64, ReLU (k-split across 2 waves) ----
    {
        const float* wp = fc_w + j * 512 + w * 256;
        const float* ap = a2 + w * 256;
        float s0a = 0.f, s1a = 0.f, s2a = 0.f, s3a = 0.f;
        for (int k = 0; k < 256; k += 4) {
            s0a = fmaf(ap[k + 0], wp[k + 0], s0a);
            s1a = fmaf(ap[k + 1], wp[k + 1], s1a);
            s2a = fmaf(ap[k + 2], wp[k + 2], s2a);
            s3a = fmaf(ap[k + 3], wp[k + 3], s3a);
        }
        pfc[tid] = (s0a + s1a) + (s2a + s3a);
    }
    __syncthreads();
    if (tid < 64) semb[tid] = fmaxf(pfc[tid] + pfc[tid + 64] + fc_b[tid], 0.0f);
    __syncthreads();

    // ---- step-invariant gx ----
    {
        const float* bz = b_z + (size_t)(bn / N_ENV) * LATENT_D;
        for (int g = tid; g < 192; g += 128) {
            float sum = gru_bih[g] + ((g < 128) ? gru_bhh[g] : 0.0f);
            const float* wp = gru_wih + g * GRU_IN_D;
            for (int k = 0; k < 64; ++k) sum = fmaf(semb[k], wp[k], sum);
            for (int k = 0; k < 64; ++k) sum = fmaf(bz[k], wp[70 + k], sum);
            gxc[g] = sum;
        }
    }
    // ---- action table ----
    for (int i = tid; i < 6 * 192; i += 128) {
        const int a = i / 192, g = i % 192;
        float sum = 0.0f;
        #pragma unroll
        for (int q = 0; q < 6; ++q)
            sum = fmaf(emb[a * 6 + q], gru_wih[g * GRU_IN_D + 64 + q], sum);
        atab[i] = sum;
    }
    __syncthreads();

    if (w == 1) return;   // rollout is single-wave; wave 1 exits

    // ---- per-lane fp32 weights in the unified VGPR/AGPR file ----
    // lane j: whh rows {j, 64+j, 128+j} + mlp1 row j = 256 f32
    f2 wr[32], wz[32], wn[32], w1[32];
    {
        const float* pr = gru_whh + (size_t)j * 64;
        const float* pz = gru_whh + (size_t)(64 + j) * 64;
        const float* pn = gru_whh + (size_t)(128 + j) * 64;
        const float* p1 = mlp1_w + (size_t)j * 64;
        #pragma unroll
        for (int i = 0; i < 16; ++i) {
            float4 v;
            v = ((const float4*)pr)[i]; wr[2*i] = (f2){v.x, v.y}; wr[2*i+1] = (f2){v.z, v.w};
            v = ((const float4*)pz)[i]; wz[2*i] = (f2){v.x, v.y}; wz[2*i+1] = (f2){v.z, v.w};
            v = ((const float4*)pn)[i]; wn[2*i] = (f2){v.x, v.y}; wn[2*i+1] = (f2){v.z, v.w};
            v = ((const float4*)p1)[i]; w1[2*i] = (f2){v.x, v.y}; w1[2*i+1] = (f2){v.z, v.w};
        }
    }
    const float gxr = gxc[j], gxz = gxc[64 + j], gxn = gxc[128 + j];
    const float bhn = gru_bhh[128 + j];
    const float b1j = mlp1_b[j];
    float ar[6], az[6], an[6], m2c[6], b2[6];
    #pragma unroll
    for (int a = 0; a < 6; ++a) {
        ar[a] = atab[a * 192 + j];
        az[a] = atab[a * 192 + 64 + j];
        an[a] = atab[a * 192 + 128 + j];
        m2c[a] = mlp2_w[a * 64 + j];
        b2[a] = mlp2_b[a];
    }

    // ---- rollout: single wave, fp32, no barriers ----
    float hprev = 0.0f;
    float hr_c = 0.0f, hz_c = 0.0f, hn_c = bhn;   // gh dots for h_0 = 0
    int act = A_DIM - 1;
    float* lout = logits_out + (size_t)bn * (T_STEPS - 1) * A_DIM;
    const float4* hb = (const float4*)hbuf;       // 16 x 16B

    for (int t = 0; t < T_STEPS - 1; ++t) {
        // act is wave-uniform; select action contribution from registers
        float sr = ar[0], sz = az[0], sn = an[0];
        #pragma unroll
        for (int a = 1; a < 6; ++a) {
            const bool c = (act == a);
            sr = c ? ar[a] : sr; sz = c ? az[a] : sz; sn = c ? an[a] : sn;
        }
        const float r = fast_sigmoid(gxr + sr + hr_c);
        const float z = fast_sigmoid(gxz + sz + hz_c);
        const float n = fast_tanh(fmaf(r, hn_c, gxn + sn));
        const float hnew = fmaf(z, hprev - n, n);
        hprev = hnew;

        // broadcast hnew through LDS (same-wave, in-order DS pipe)
        __builtin_amdgcn_wave_barrier();
        hbuf[j] = hnew;
        __builtin_amdgcn_wave_barrier();

        // fused sweep: mlp1 partials FIRST (so the argmax tail can start
        // while the gh FMAs are still issuing), then r/z/n dots
        f2 p1 = {0.f, 0.f}, pr = {0.f, 0.f}, pz = {0.f, 0.f}, pn = {0.f, 0.f};
        #pragma unroll
        for (int i = 0; i < 16; ++i) {
            const float4 hv = hb[i];
            const f2 ha = (f2){hv.x, hv.y};
            const f2 hc = (f2){hv.z, hv.w};
            p1 += ha * w1[2*i]; p1 += hc * w1[2*i+1];
            pr += ha * wr[2*i]; pr += hc * wr[2*i+1];
            pz += ha * wz[2*i]; pz += hc * wz[2*i+1];
            pn += ha * wn[2*i]; pn += hc * wn[2*i+1];
        }
        hr_c = pr.x + pr.y;
        hz_c = pz.x + pz.y;
        hn_c = pn.x + pn.y + bhn;
        const float hid = fast_tanh(p1.x + p1.y + b1j);

        // mlp2 + argmax via DPP wave reduction (VALU pipe)
        const float l0 = wave_reduce_add(hid * m2c[0]) + b2[0];
        const float l1 = wave_reduce_add(hid * m2c[1]) + b2[1];
        const float l2 = wave_reduce_add(hid * m2c[2]) + b2[2];
        const float l3 = wave_reduce_add(hid * m2c[3]) + b2[3];
        const float l4 = wave_reduce_add(hid * m2c[4]) + b2[4];
        const float l5 = wave_reduce_add(hid * m2c[5]) + b2[5];

        float best = l0; int bi = 0;
        if (l1 > best) { best = l1; bi = 1; }
        if (l2 > best) { best = l2; bi = 2; }
        if (l3 > best) { best = l3; bi = 3; }
        if (l4 > best) { best = l4; bi = 4; }
        if (l5 > best) { best = l5; bi = 5; }
        act = bi;

        if (j < A_DIM) {
            const float outv = (j == 0) ? l0 : (j == 1) ? l1 : (j == 2) ? l2
                             : (j == 3) ? l3 : (j == 4) ? l4 : l5;
            lout[t * A_DIM + j] = outv;
        }
    }
}

extern "C" void kernel_launch(void* const* d_in, const int* in_sizes, int n_in,
                              void* d_out, int out_size, void* d_ws, size_t ws_size,
                              hipStream_t stream) {
    const float* s_h     = (const float*)d_in[0];
    const int*   a_h     = (const int*)  d_in[1];
    const float* b_z     = (const float*)d_in[2];
    const float* conv1_w = (const float*)d_in[3];
    const float* conv1_b = (const float*)d_in[4];
    const float* conv2_w = (const float*)d_in[5];
    const float* conv2_b = (const float*)d_in[6];
    const float* fc_w    = (const float*)d_in[7];
    const float* fc_b    = (const float*)d_in[8];
    const float* emb     = (const float*)d_in[9];
    const float* gru_wih = (const float*)d_in[10];
    const float* gru_whh = (const float*)d_in[11];
    const float* gru_bih = (const float*)d_in[12];
    const float* gru_bhh = (const float*)d_in[13];
    const float* mlp1_w  = (const float*)d_in[14];
    const float* mlp1_b  = (const float*)d_in[15];
    const float* mlp2_w  = (const float*)d_in[16];
    const float* mlp2_b  = (const float*)d_in[17];

    float* out = (float*)d_out;
    float* logits_out = out;                                          // (B,N,127,6)
    float* mask_out   = out + (size_t)BN_TOT * (T_STEPS - 1) * A_DIM; // (B,N,128,1)

    policy_kernel<<<BN_TOT, 128, 0, stream>>>(
        s_h, a_h, b_z, conv1_w, conv1_b, conv2_w, conv2_b, fc_w, fc_b, emb,
        gru_wih, gru_whh, gru_bih, gru_bhh, mlp1_w, mlp1_b, mlp2_w, mlp2_b,
        logits_out, mask_out);
}

// Round 6
// 480.861 us; speedup vs baseline: 1.2820x; 1.0042x over previous
//
#include <hip/hip_runtime.h>

#define A_DIM 6
#define HID_D 64
#define LATENT_D 64
#define GRU_IN_D 134
#define T_STEPS 128
#define N_ENV 10
#define BN_TOT 640

typedef float f2 __attribute__((ext_vector_type(2)));

__device__ __forceinline__ float fast_sigmoid(float x) {
    return __builtin_amdgcn_rcpf(1.0f + __builtin_amdgcn_exp2f(-1.4426950408889634f * x));
}
__device__ __forceinline__ float fast_tanh(float x) {
    return 1.0f - 2.0f * __builtin_amdgcn_rcpf(1.0f + __builtin_amdgcn_exp2f(2.8853900817779268f * x));
}

template<int CTRL>
__device__ __forceinline__ float dppadd(float v) {
    int t = __builtin_amdgcn_update_dpp(0, __builtin_bit_cast(int, v), CTRL, 0xf, 0xf, true);
    return v + __builtin_bit_cast(float, t);
}
// sum over all 64 lanes -> wave-uniform scalar (VALU pipe only)
__device__ __forceinline__ float wave_reduce_add(float v) {
    v = dppadd<0x111>(v);   // row_shr:1
    v = dppadd<0x112>(v);   // row_shr:2
    v = dppadd<0x114>(v);   // row_shr:4
    v = dppadd<0x118>(v);   // row_shr:8
    v = dppadd<0x142>(v);   // row_bcast:15
    v = dppadd<0x143>(v);   // row_bcast:31 -> lane 63 has total
    return __builtin_bit_cast(float, __builtin_amdgcn_readlane(__builtin_bit_cast(int, v), 63));
}

__global__ __launch_bounds__(128, 1)
void policy_kernel(const float* __restrict__ s_h,
                   const int*   __restrict__ a_h,
                   const float* __restrict__ b_z,
                   const float* __restrict__ conv1_w, const float* __restrict__ conv1_b,
                   const float* __restrict__ conv2_w, const float* __restrict__ conv2_b,
                   const float* __restrict__ fc_w,    const float* __restrict__ fc_b,
                   const float* __restrict__ emb,
                   const float* __restrict__ gru_wih, const float* __restrict__ gru_whh,
                   const float* __restrict__ gru_bih, const float* __restrict__ gru_bhh,
                   const float* __restrict__ mlp1_w,  const float* __restrict__ mlp1_b,
                   const float* __restrict__ mlp2_w,  const float* __restrict__ mlp2_b,
                   float* __restrict__ logits_out, float* __restrict__ mask_out)
{
    __shared__ __align__(16) float s0[512];      // frame0 [c][h][w]
    __shared__ __align__(16) float a1[1152];     // conv1 out [32][36]
    __shared__ __align__(16) float a2[512];      // conv2 out flat
    __shared__ __align__(16) float pfc[128];     // fc partials
    __shared__ __align__(16) float semb[64];
    __shared__ __align__(16) float gxc[192];     // step-invariant gx (+biases)
    __shared__ __align__(16) float atab[6*192];  // per-action gx contribution
    __shared__ __align__(16) float hspec[6*64];  // speculative h_{t+1} per action

    const int bn  = blockIdx.x;          // 0..639
    const int tid = threadIdx.x;         // 0..127 (preamble); rollout = wave 0 only
    const int j   = tid & 63;
    const int w   = tid >> 6;

    // ---- masks output ----
    mask_out[bn * T_STEPS + tid] = (a_h[bn * T_STEPS + tid] != (A_DIM - 1)) ? 1.0f : 0.0f;

    // ---- load frame 0 ----
    {
        const float* src = s_h + (size_t)bn * T_STEPS * 512;
        #pragma unroll
        for (int i = 0; i < 4; ++i) s0[tid + i * 128] = src[tid + i * 128];
    }
    __syncthreads();

    // ---- conv1: (8,8,8) -> (32,6,6), ReLU ----
    for (int i = tid; i < 1152; i += 128) {
        const int oc = i / 36, r = i % 36, oh = r / 6, ow = r % 6;
        float sum = conv1_b[oc];
        const float* wp = conv1_w + oc * 72;
        #pragma unroll
        for (int ic = 0; ic < 8; ++ic)
            #pragma unroll
            for (int kh = 0; kh < 3; ++kh)
                #pragma unroll
                for (int kw = 0; kw < 3; ++kw)
                    sum = fmaf(s0[ic * 64 + (oh + kh) * 8 + (ow + kw)],
                               wp[ic * 9 + kh * 3 + kw], sum);
        a1[i] = fmaxf(sum, 0.0f);
    }
    __syncthreads();

    // ---- conv2: (32,6,6) -> (32,4,4), ReLU ----
    for (int i = tid; i < 512; i += 128) {
        const int oc = i / 16, r = i % 16, oh = r / 4, ow = r % 4;
        float sum = conv2_b[oc];
        const float* wp = conv2_w + oc * 288;
        for (int ic = 0; ic < 32; ++ic)
            #pragma unroll
            for (int kh = 0; kh < 3; ++kh)
                #pragma unroll
                for (int kw = 0; kw < 3; ++kw)
                    sum = fmaf(a1[ic * 36 + (oh + kh) * 6 + (ow + kw)],
                               wp[ic * 9 + kh * 3 + kw], sum);
        a2[i] = fmaxf(sum, 0.0f);
    }
    __syncthreads();

    // ---- fc: 512 -> 64, ReLU (k-split across 2 waves) ----
    {
        const float* wp = fc_w + j * 512 + w * 256;
        const float* ap = a2 + w * 256;
        float s0a = 0.f, s1a = 0.f, s2a = 0.f, s3a = 0.f;
        for (int k = 0; k < 256; k += 4) {
            s0a = fmaf(ap[k + 0], wp[k + 0], s0a);
            s1a = fmaf(ap[k + 1], wp[k + 1], s1a);
            s2a = fmaf(ap[k + 2], wp[k + 2], s2a);
            s3a = fmaf(ap[k + 3], wp[k + 3], s3a);
        }
        pfc[tid] = (s0a + s1a) + (s2a + s3a);
    }
    __syncthreads();
    if (tid < 64) semb[tid] = fmaxf(pfc[tid] + pfc[tid + 64] + fc_b[tid], 0.0f);
    __syncthreads();

    // ---- step-invariant gx ----
    {
        const float* bz = b_z + (size_t)(bn / N_ENV) * LATENT_D;
        for (int g = tid; g < 192; g += 128) {
            float sum = gru_bih[g] + ((g < 128) ? gru_bhh[g] : 0.0f);
            const float* wp = gru_wih + g * GRU_IN_D;
            for (int k = 0; k < 64; ++k) sum = fmaf(semb[k], wp[k], sum);
            for (int k = 0; k < 64; ++k) sum = fmaf(bz[k], wp[70 + k], sum);
            gxc[g] = sum;
        }
    }
    // ---- action table ----
    for (int i = tid; i < 6 * 192; i += 128) {
        const int a = i / 192, g = i % 192;
        float sum = 0.0f;
        #pragma unroll
        for (int q = 0; q < 6; ++q)
            sum = fmaf(emb[a * 6 + q], gru_wih[g * GRU_IN_D + 64 + q], sum);
        atab[i] = sum;
    }
    __syncthreads();

    if (w == 1) return;   // rollout is single-wave; wave 1 exits

    // ---- per-lane fp32 weights ----
    f2 wr[32], wz[32], wn[32], w1[32];
    {
        const float* pr = gru_whh + (size_t)j * 64;
        const float* pz = gru_whh + (size_t)(64 + j) * 64;
        const float* pn = gru_whh + (size_t)(128 + j) * 64;
        const float* p1 = mlp1_w + (size_t)j * 64;
        #pragma unroll
        for (int i = 0; i < 16; ++i) {
            float4 v;
            v = ((const float4*)pr)[i]; wr[2*i] = (f2){v.x, v.y}; wr[2*i+1] = (f2){v.z, v.w};
            v = ((const float4*)pz)[i]; wz[2*i] = (f2){v.x, v.y}; wz[2*i+1] = (f2){v.z, v.w};
            v = ((const float4*)pn)[i]; wn[2*i] = (f2){v.x, v.y}; wn[2*i+1] = (f2){v.z, v.w};
            v = ((const float4*)p1)[i]; w1[2*i] = (f2){v.x, v.y}; w1[2*i+1] = (f2){v.z, v.w};
        }
    }
    const float bhn = gru_bhh[128 + j];
    const float b1j = mlp1_b[j];
    // step-invariant per-action gate inputs: arx[a] = gx_r + atab_r[a], etc.
    float arx[6], azx[6], anx[6], m2c[6], b2[6];
    {
        const float gxr = gxc[j], gxz = gxc[64 + j], gxn = gxc[128 + j];
        #pragma unroll
        for (int a = 0; a < 6; ++a) {
            arx[a] = gxr + atab[a * 192 + j];
            azx[a] = gxz + atab[a * 192 + 64 + j];
            anx[a] = gxn + atab[a * 192 + 128 + j];
            m2c[a] = mlp2_w[a * 64 + j];
            b2[a] = mlp2_b[a];
        }
    }

    // ---- seed: speculative h_1 candidates from h_0 = 0 ----
    // dots(h_0): hr = hz = 0, hn = bhn
    float ha[6];
    #pragma unroll
    for (int a = 0; a < 6; ++a) {
        const float r = fast_sigmoid(arx[a]);
        const float z = fast_sigmoid(azx[a]);
        const float n = fast_tanh(fmaf(r, bhn, anx[a]));
        ha[a] = fmaf(z, 0.0f - n, n);            // (1-z)*n + z*0
    }
    __builtin_amdgcn_wave_barrier();
    #pragma unroll
    for (int a = 0; a < 6; ++a) hspec[a * 64 + j] = ha[a];
    __builtin_amdgcn_wave_barrier();

    int act = A_DIM - 1;
    float* lout = logits_out + (size_t)bn * (T_STEPS - 1) * A_DIM;

    for (int t = 0; t < T_STEPS - 1; ++t) {
        // critical path: act -> address -> sweep of h_{t+1} = hspec[act]
        const float4* hb = (const float4*)(hspec + (act << 6));
        // h_{t+1}[j] for this lane (for next speculative gates; off critical path)
        float hprev = ha[0];
        #pragma unroll
        for (int a = 1; a < 6; ++a) hprev = (act == a) ? ha[a] : hprev;

        // fused sweep: mlp1 (2 chains, finishes first) + r/z/n dots
        f2 p1a = {0.f, 0.f}, p1b = {0.f, 0.f};
        f2 pr = {0.f, 0.f}, pz = {0.f, 0.f}, pn = {0.f, 0.f};
        #pragma unroll
        for (int i = 0; i < 16; ++i) {
            const float4 hv = hb[i];
            const f2 haa = (f2){hv.x, hv.y};
            const f2 hcc = (f2){hv.z, hv.w};
            p1a += haa * w1[2*i]; p1b += hcc * w1[2*i+1];
            pr += haa * wr[2*i]; pr += hcc * wr[2*i+1];
            pz += haa * wz[2*i]; pz += hcc * wz[2*i+1];
            pn += haa * wn[2*i]; pn += hcc * wn[2*i+1];
        }
        const f2 p1 = p1a + p1b;
        const float hid = fast_tanh(p1.x + p1.y + b1j);
        const float hr = pr.x + pr.y;
        const float hz = pz.x + pz.y;
        const float hn = pn.x + pn.y + bhn;

        // mlp2 via DPP wave reduction (critical path: hid -> l -> argmax)
        const float l0 = wave_reduce_add(hid * m2c[0]) + b2[0];
        const float l1 = wave_reduce_add(hid * m2c[1]) + b2[1];
        const float l2 = wave_reduce_add(hid * m2c[2]) + b2[2];
        const float l3 = wave_reduce_add(hid * m2c[3]) + b2[3];
        const float l4 = wave_reduce_add(hid * m2c[4]) + b2[4];
        const float l5 = wave_reduce_add(hid * m2c[5]) + b2[5];

        // speculative gates for ALL 6 actions (independent of argmax; fills
        // the DPP latency window). Produces candidate h_{t+2} values.
        #pragma unroll
        for (int a = 0; a < 6; ++a) {
            const float r = fast_sigmoid(arx[a] + hr);
            const float z = fast_sigmoid(azx[a] + hz);
            const float n = fast_tanh(fmaf(r, hn, anx[a]));
            ha[a] = fmaf(z, hprev - n, n);
        }
        __builtin_amdgcn_wave_barrier();
        #pragma unroll
        for (int a = 0; a < 6; ++a) hspec[a * 64 + j] = ha[a];
        __builtin_amdgcn_wave_barrier();

        // argmax, first-max-wins
        float best = l0; int bi = 0;
        if (l1 > best) { best = l1; bi = 1; }
        if (l2 > best) { best = l2; bi = 2; }
        if (l3 > best) { best = l3; bi = 3; }
        if (l4 > best) { best = l4; bi = 4; }
        if (l5 > best) { best = l5; bi = 5; }
        act = bi;

        if (j < A_DIM) {
            const float outv = (j == 0) ? l0 : (j == 1) ? l1 : (j == 2) ? l2
                             : (j == 3) ? l3 : (j == 4) ? l4 : l5;
            lout[t * A_DIM + j] = outv;
        }
    }
}

extern "C" void kernel_launch(void* const* d_in, const int* in_sizes, int n_in,
                              void* d_out, int out_size, void* d_ws, size_t ws_size,
                              hipStream_t stream) {
    const float* s_h     = (const float*)d_in[0];
    const int*   a_h     = (const int*)  d_in[1];
    const float* b_z     = (const float*)d_in[2];
    const float* conv1_w = (const float*)d_in[3];
    const float* conv1_b = (const float*)d_in[4];
    const float* conv2_w = (const float*)d_in[5];
    const float* conv2_b = (const float*)d_in[6];
    const float* fc_w    = (const float*)d_in[7];
    const float* fc_b    = (const float*)d_in[8];
    const float* emb     = (const float*)d_in[9];
    const float* gru_wih = (const float*)d_in[10];
    const float* gru_whh = (const float*)d_in[11];
    const float* gru_bih = (const float*)d_in[12];
    const float* gru_bhh = (const float*)d_in[13];
    const float* mlp1_w  = (const float*)d_in[14];
    const float* mlp1_b  = (const float*)d_in[15];
    const float* mlp2_w  = (const float*)d_in[16];
    const float* mlp2_b  = (const float*)d_in[17];

    float* out = (float*)d_out;
    float* logits_out = out;                                          // (B,N,127,6)
    float* mask_out   = out + (size_t)BN_TOT * (T_STEPS - 1) * A_DIM; // (B,N,128,1)

    policy_kernel<<<BN_TOT, 128, 0, stream>>>(
        s_h, a_h, b_z, conv1_w, conv1_b, conv2_w, conv2_b, fc_w, fc_b, emb,
        gru_wih, gru_whh, gru_bih, gru_bhh, mlp1_w, mlp1_b, mlp2_w, mlp2_b,
        logits_out, mask_out);
}